// Round 16
// baseline (956.280 us; speedup 1.0000x reference)
//
#include <hip/hip_runtime.h>
#include <hip/hip_bf16.h>
#include <math.h>

#define TT 8192
#define HD 1024
#define FHD 4096
#define NE 8
#define NTMAX 136
#define NWG1 4352

typedef short s16x8 __attribute__((ext_vector_type(8)));
typedef float f32x4 __attribute__((ext_vector_type(4)));
using bf16 = __hip_bfloat16;
typedef unsigned int u32;

// workspace layout (bytes)
#define OFF_COUNTS 0            // counts[0..7], done at +32
#define OFF_DONE   32
#define OFF_CURSOR 64
#define OFF_OFFS   128
#define OFF_E0     256
#define OFF_E1     (OFF_E0 + 4*TT)
#define OFF_W0     (OFF_E1 + 4*TT)
#define OFF_W1     (OFF_W0 + 4*TT)
#define OFF_S0     (OFF_W1 + 4*TT)
#define OFF_S1     (OFF_S0 + 4*TT)
#define OFF_TID    (OFF_S1 + 4*TT)
#define OFF_TW     (OFF_TID + 8*TT)
#define OFF_TMR    (OFF_TW + 8*TT)
#define OFF_TME    (OFF_TMR + 4*144)
#define OFF_TMN    (OFF_TME + 4*144)
#define OFF_XBF    (OFF_TMN + 64)
#define OFF_W1T    (OFF_XBF + 2*TT*HD)
#define OFF_W2T    (OFF_W1T + 2*NE*HD*FHD)
#define OFF_HMID   (OFF_W2T + 2*NE*HD*FHD)
#define OFF_YS     (OFF_HMID + (size_t)2*(2*TT)*FHD)

__device__ __forceinline__ void gload_lds16(const void* g, void* l) {
    __builtin_amdgcn_global_load_lds(
        (const __attribute__((address_space(1))) u32*)g,
        (__attribute__((address_space(3))) u32*)l, 16, 0, 0);
}

// transpose+cast one 256k x 64n panel (R9-proven code), using caller's smem
__device__ __forceinline__ void transpose_panel(const float* __restrict__ in,
        bf16* __restrict__ out, int R, int C, int rem, int tid, char* smem) {
    float (*tile)[65]  = reinterpret_cast<float(*)[65]>(smem);          // 16640 B
    bf16  (*btile)[264] = reinterpret_cast<bf16(*)[264]>(smem + 16640); // 33792 B
    int kch = R >> 8, nch = C >> 6;
    int per = kch * nch;
    int e = rem / per;
    int rem2 = rem % per;
    int kc = rem2 / nch, nc = rem2 % nch;
    int k0 = kc << 8, n0 = nc << 6;
    const float* ine = in + (size_t)e * R * C;
    bf16* oute = out + (size_t)e * R * C;
    for (int s = 0; s < 4; ++s) {
        int ks = k0 + s * 64;
#pragma unroll
        for (int i = 0; i < 4; ++i) {
            int lin = tid + i * 256;
            int r = lin >> 4, cg = lin & 15;
            float4 v = *reinterpret_cast<const float4*>(&ine[(size_t)(ks + r) * C + n0 + cg * 4]);
            tile[r][cg * 4 + 0] = v.x; tile[r][cg * 4 + 1] = v.y;
            tile[r][cg * 4 + 2] = v.z; tile[r][cg * 4 + 3] = v.w;
        }
        __syncthreads();
#pragma unroll
        for (int i = 0; i < 4; ++i) {
            int lin = tid + i * 256;
            int n = lin >> 4, kg = lin & 15;
            bf16 h[4];
            h[0] = __float2bfloat16(tile[kg * 4 + 0][n]);
            h[1] = __float2bfloat16(tile[kg * 4 + 1][n]);
            h[2] = __float2bfloat16(tile[kg * 4 + 2][n]);
            h[3] = __float2bfloat16(tile[kg * 4 + 3][n]);
            *reinterpret_cast<uint2*>(&btile[n][s * 64 + kg * 4]) = *reinterpret_cast<uint2*>(h);
        }
        __syncthreads();
    }
#pragma unroll
    for (int i = 0; i < 8; ++i) {
        int lin = tid + i * 256;
        int n = lin >> 5, kk = lin & 31;
        *reinterpret_cast<uint4*>(&oute[(size_t)(n0 + n) * R + k0 + kk * 8]) =
            *reinterpret_cast<const uint4*>(&btile[n][kk * 8]);
    }
}

// ---------------- fused1: transpose w1 (blocks 0..2047) || router+cast+scan ----------------
__global__ __launch_bounds__(256) void fused1_kernel(
        const float* __restrict__ x, const float* __restrict__ rw, const float* __restrict__ rb,
        const float* __restrict__ w1, bf16* __restrict__ xbf, bf16* __restrict__ w1t,
        int* __restrict__ e0a, int* __restrict__ e1a,
        float* __restrict__ w0a, float* __restrict__ w1a,
        int* __restrict__ counts, int* __restrict__ done,
        int* __restrict__ offs, int* __restrict__ cursor,
        int* __restrict__ tmr, int* __restrict__ tme, int* __restrict__ tmn) {
    __shared__ __attribute__((aligned(16))) char smem[50432];
    int bid = blockIdx.x;
    int tid = threadIdx.x;
    if (bid < 2048) {
        transpose_panel(w1, w1t, HD, FHD, bid, tid, smem);
        return;
    }
    // ---- router (+cast) ----
    int rbid = bid - 2048;
    int wid = tid >> 6, lane = tid & 63;
    int t = rbid * 4 + wid;
    const float* xp = x + (size_t)t * HD + lane * 16;
    float xv[16];
#pragma unroll
    for (int j = 0; j < 4; ++j) {
        float4 v = *reinterpret_cast<const float4*>(&xp[j * 4]);
        xv[4 * j] = v.x; xv[4 * j + 1] = v.y; xv[4 * j + 2] = v.z; xv[4 * j + 3] = v.w;
    }
    {
        bf16 hv[16];
#pragma unroll
        for (int j = 0; j < 16; ++j) hv[j] = __float2bfloat16(xv[j]);
        uint4* dst = reinterpret_cast<uint4*>(&xbf[(size_t)t * HD + lane * 16]);
        dst[0] = reinterpret_cast<uint4*>(hv)[0];
        dst[1] = reinterpret_cast<uint4*>(hv)[1];
    }
    float acc[8] = {0.f, 0.f, 0.f, 0.f, 0.f, 0.f, 0.f, 0.f};
    const float* rp = rw + (size_t)(lane * 16) * NE;
#pragma unroll
    for (int hh = 0; hh < 16; ++hh) {
        float4 r0 = *reinterpret_cast<const float4*>(&rp[hh * 8]);
        float4 r1 = *reinterpret_cast<const float4*>(&rp[hh * 8 + 4]);
        acc[0] += xv[hh] * r0.x; acc[1] += xv[hh] * r0.y;
        acc[2] += xv[hh] * r0.z; acc[3] += xv[hh] * r0.w;
        acc[4] += xv[hh] * r1.x; acc[5] += xv[hh] * r1.y;
        acc[6] += xv[hh] * r1.z; acc[7] += xv[hh] * r1.w;
    }
#pragma unroll
    for (int e = 0; e < 8; ++e) {
#pragma unroll
        for (int off = 32; off > 0; off >>= 1) acc[e] += __shfl_xor(acc[e], off, 64);
    }
    if (lane == 0) {
        float lg[8];
#pragma unroll
        for (int e = 0; e < 8; ++e) lg[e] = acc[e] + rb[e];
        int a = 0;
#pragma unroll
        for (int e = 1; e < 8; ++e) if (lg[e] > lg[a]) a = e;
        int b = (a == 0) ? 1 : 0;
#pragma unroll
        for (int e = 0; e < 8; ++e) if (e != a && e != b && lg[e] > lg[b]) b = e;
        float wa = 1.0f / (1.0f + expf(lg[b] - lg[a]));
        float wb = 1.0f / (1.0f + expf(lg[a] - lg[b]));
        e0a[t] = a; e1a[t] = b; w0a[t] = wa; w1a[t] = wb;
        atomicAdd(&counts[a], 1);
        atomicAdd(&counts[b], 1);
    }
    __syncthreads();
    __shared__ int lastFlag;
    if (tid == 0) {
        __threadfence();
        lastFlag = (atomicAdd(done, 1) == 2047) ? 1 : 0;
    }
    __syncthreads();
    if (!lastFlag) return;
    __threadfence();
    __shared__ int cbase[NE + 1], tbase[NE + 1];
    if (tid == 0) {
        int s = 0, ntt = 0;
        for (int e = 0; e < NE; ++e) {
            int c = atomicAdd(&counts[e], 0);
            cbase[e] = s; tbase[e] = ntt;
            s += c; ntt += (c + 127) >> 7;
        }
        cbase[NE] = s; tbase[NE] = ntt;
        tmn[0] = ntt;
        offs[NE] = s;
    }
    __syncthreads();
    if (tid < NE) { offs[tid] = cbase[tid]; cursor[tid] = cbase[tid]; }
    if (tid < NTMAX) {
        int ntt = tbase[NE];
        if (tid < ntt) {
            int e = 0;
            while (tbase[e + 1] <= tid) ++e;
            tmr[tid] = cbase[e] + ((tid - tbase[e]) << 7);
            tme[tid] = e;
        } else { tmr[tid] = 0; tme[tid] = 0; }
    }
}

__global__ __launch_bounds__(256) void scatter_kernel(const int* __restrict__ e0a, const int* __restrict__ e1a,
        const float* __restrict__ w0a, const float* __restrict__ w1a,
        int* __restrict__ cursor, int* __restrict__ tid_arr, float* __restrict__ tw_arr,
        int* __restrict__ slot0, int* __restrict__ slot1) {
    int t = blockIdx.x * 256 + threadIdx.x;
    int s0 = atomicAdd(&cursor[e0a[t]], 1);
    tid_arr[s0] = t; tw_arr[s0] = w0a[t]; slot0[t] = s0;
    int s1 = atomicAdd(&cursor[e1a[t]], 1);
    tid_arr[s1] = t; tw_arr[s1] = w1a[t]; slot1[t] = s1;
}

// ---------------- fused2: transpose w2 (blocks 0..2047) || gemm1 ----------------
// gemm1: 2D supertile decode (17 tidx x 8 nt); BK=64, single LDS buffer,
// R5-proven both-sides XOR swizzle ([row][64] rows are 128B -> 16-way conflict
// without it, G4).
__global__ __launch_bounds__(256) void fused2_kernel(
        const float* __restrict__ w2, bf16* __restrict__ w2t,
        const bf16* __restrict__ xbf, const bf16* __restrict__ w1t,
        const float* __restrict__ b1, const int* __restrict__ offs,
        const int* __restrict__ tid_arr, bf16* __restrict__ hmid,
        const int* __restrict__ tmr, const int* __restrict__ tme, const int* __restrict__ tmn) {
    __shared__ __attribute__((aligned(16))) char smem[50432];
    int bid = blockIdx.x;
    int tid = threadIdx.x;
    if (bid < 2048) {
        transpose_panel(w2, w2t, FHD, HD, bid, tid, smem);
        return;
    }
    // ---- gemm1 section: As[128][64], Bs[128][64], toks ----
    bf16* As = reinterpret_cast<bf16*>(smem);            // 16384 B
    bf16* Bs = reinterpret_cast<bf16*>(smem + 16384);    // 16384 B
    int*  toks = reinterpret_cast<int*>(smem + 32768);   // 512 B
    int orig = bid - 2048;                 // 0..4351
    int wg = (orig & 7) * (NWG1 >> 3) + (orig >> 3);
    int st = wg / 136, within = wg % 136;
    int tidx = (st >> 2) * 17 + (within % 17);
    int nt = (st & 3) * 8 + (within / 17);
    if (tidx >= tmn[0]) return;
    int e = tme[tidx];
    int row0 = tmr[tidx];
    int s1 = offs[e + 1];
    int n0 = nt * 128;
    if (tid < 128) { int s = row0 + tid; toks[tid] = tid_arr[(s < s1) ? s : (s1 - 1)]; }
    __syncthreads();
    int lane = tid & 63, w = tid >> 6;
    int wrow = (w >> 1) * 64, wcol = (w & 1) * 64;
    int lr = lane & 15, kg = lane >> 4;
    // staging: thread covers rows {srow, +32, +64, +96}, source octet pre-swizzled
    int srow = tid >> 3, oct = tid & 7;
    int socts = (oct ^ (srow & 7)) * 8;
    const bf16* w1e = w1t + (size_t)e * FHD * HD;
    const bf16* pA[4]; const bf16* pB[4];
#pragma unroll
    for (int i = 0; i < 4; ++i) {
        int r = i * 32 + srow;
        pA[i] = xbf + (size_t)toks[r] * HD + socts;
        pB[i] = w1e + (size_t)(n0 + r) * HD + socts;
    }
    int ldst = tid * 8;               // elems; + i*2048
    // swizzled fragment k-offsets
    int koff0 = (kg * 8) ^ ((lr & 7) << 3);
    int koff1 = (32 + kg * 8) ^ ((lr & 7) << 3);
    f32x4 acc[4][4] = {};
    for (int k0 = 0; k0 < HD; k0 += 64) {
#pragma unroll
        for (int i = 0; i < 4; ++i) {
            gload_lds16(pA[i] + k0, &As[i * 2048 + ldst]);
            gload_lds16(pB[i] + k0, &Bs[i * 2048 + ldst]);
        }
        __syncthreads();
        s16x8 aF[4][2], bF[4][2];
#pragma unroll
        for (int m = 0; m < 4; ++m) {
            int rowA = wrow + m * 16 + lr;
            int rowB = wcol + m * 16 + lr;
            aF[m][0] = *reinterpret_cast<const s16x8*>(&As[rowA * 64 + koff0]);
            aF[m][1] = *reinterpret_cast<const s16x8*>(&As[rowA * 64 + koff1]);
            bF[m][0] = *reinterpret_cast<const s16x8*>(&Bs[rowB * 64 + koff0]);
            bF[m][1] = *reinterpret_cast<const s16x8*>(&Bs[rowB * 64 + koff1]);
        }
        __builtin_amdgcn_s_setprio(1);
#pragma unroll
        for (int m = 0; m < 4; ++m)
#pragma unroll
            for (int n = 0; n < 4; ++n)
#pragma unroll
                for (int s = 0; s < 2; ++s)
                    acc[m][n] = __builtin_amdgcn_mfma_f32_16x16x32_bf16(aF[m][s], bF[n][s], acc[m][n], 0, 0, 0);
        __builtin_amdgcn_s_setprio(0);
        __syncthreads();
    }
#pragma unroll
    for (int m = 0; m < 4; ++m) {
#pragma unroll
        for (int n = 0; n < 4; ++n) {
            int col = n0 + wcol + n * 16 + lr;
            float bv = b1[(size_t)e * FHD + col];
#pragma unroll
            for (int r = 0; r < 4; ++r) {
                int row = wrow + m * 16 + kg * 4 + r;
                int slot = row0 + row;
                if (slot < s1) {
                    float v2 = acc[m][n][r] + bv;
                    v2 = 0.5f * v2 * (1.0f + erff(v2 * 0.70710678118f));
                    hmid[(size_t)slot * FHD + col] = __float2bfloat16(v2);
                }
            }
        }
    }
}

// GEMM2: 2D supertile decode (17 tidx x 4 nt); BK=64 single buffer, swizzled.
__global__ __launch_bounds__(256) void gemm2_kernel(const bf16* __restrict__ hmid, const bf16* __restrict__ w2t,
        const float* __restrict__ b2, const int* __restrict__ offs, float* __restrict__ ys,
        const int* __restrict__ tmr, const int* __restrict__ tme, const int* __restrict__ tmn) {
    __shared__ bf16 As[128 * 64];
    __shared__ bf16 Bs[128 * 64];
    int nwg = gridDim.x;              // 1088, %8==0
    int orig = blockIdx.x;
    int wg = (orig & 7) * (nwg >> 3) + (orig >> 3);
    int st = wg / 68, within = wg % 68;
    int tidx = (st >> 1) * 17 + (within % 17);
    int nt = (st & 1) * 4 + (within / 17);
    if (tidx >= tmn[0]) return;
    int e = tme[tidx];
    int row0 = tmr[tidx];
    int s1 = offs[e + 1];
    int n0 = nt * 128;
    int tid = threadIdx.x;
    int lane = tid & 63, w = tid >> 6;
    int wrow = (w >> 1) * 64, wcol = (w & 1) * 64;
    int lr = lane & 15, kg = lane >> 4;
    int srow = tid >> 3, oct = tid & 7;
    int socts = (oct ^ (srow & 7)) * 8;
    const bf16* w2e = w2t + (size_t)e * HD * FHD;
    const bf16* pA[4]; const bf16* pB[4];
#pragma unroll
    for (int i = 0; i < 4; ++i) {
        int r = i * 32 + srow;
        int ar = row0 + r; if (ar >= s1) ar = s1 - 1;
        pA[i] = hmid + (size_t)ar * FHD + socts;
        pB[i] = w2e + (size_t)(n0 + r) * FHD + socts;
    }
    int ldst = tid * 8;
    int koff0 = (kg * 8) ^ ((lr & 7) << 3);
    int koff1 = (32 + kg * 8) ^ ((lr & 7) << 3);
    f32x4 acc[4][4] = {};
    for (int k0 = 0; k0 < FHD; k0 += 64) {
#pragma unroll
        for (int i = 0; i < 4; ++i) {
            gload_lds16(pA[i] + k0, &As[i * 2048 + ldst]);
            gload_lds16(pB[i] + k0, &Bs[i * 2048 + ldst]);
        }
        __syncthreads();
        s16x8 aF[4][2], bF[4][2];
#pragma unroll
        for (int m = 0; m < 4; ++m) {
            int rowA = wrow + m * 16 + lr;
            int rowB = wcol + m * 16 + lr;
            aF[m][0] = *reinterpret_cast<const s16x8*>(&As[rowA * 64 + koff0]);
            aF[m][1] = *reinterpret_cast<const s16x8*>(&As[rowA * 64 + koff1]);
            bF[m][0] = *reinterpret_cast<const s16x8*>(&Bs[rowB * 64 + koff0]);
            bF[m][1] = *reinterpret_cast<const s16x8*>(&Bs[rowB * 64 + koff1]);
        }
        __builtin_amdgcn_s_setprio(1);
#pragma unroll
        for (int m = 0; m < 4; ++m)
#pragma unroll
            for (int n = 0; n < 4; ++n)
#pragma unroll
                for (int s = 0; s < 2; ++s)
                    acc[m][n] = __builtin_amdgcn_mfma_f32_16x16x32_bf16(aF[m][s], bF[n][s], acc[m][n], 0, 0, 0);
        __builtin_amdgcn_s_setprio(0);
        __syncthreads();
    }
#pragma unroll
    for (int m = 0; m < 4; ++m) {
#pragma unroll
        for (int n = 0; n < 4; ++n) {
            int col = n0 + wcol + n * 16 + lr;
            float bv = b2[(size_t)e * HD + col];
#pragma unroll
            for (int r = 0; r < 4; ++r) {
                int row = wrow + m * 16 + kg * 4 + r;
                int slot = row0 + row;
                if (slot < s1) ys[(size_t)slot * HD + col] = acc[m][n][r] + bv;
            }
        }
    }
}

// out[t,:] = tw[slot0[t]] * ys[slot0[t],:] + tw[slot1[t]] * ys[slot1[t],:]
__global__ __launch_bounds__(256) void combine_kernel(const float* __restrict__ ys,
        const int* __restrict__ slot0, const int* __restrict__ slot1,
        const float* __restrict__ tw, float* __restrict__ out) {
    int t = blockIdx.x;
    int c = threadIdx.x * 4;
    int sa = slot0[t], sb = slot1[t];
    float wa = tw[sa], wb = tw[sb];
    float4 a = *reinterpret_cast<const float4*>(&ys[(size_t)sa * HD + c]);
    float4 b = *reinterpret_cast<const float4*>(&ys[(size_t)sb * HD + c]);
    float4 o;
    o.x = wa * a.x + wb * b.x; o.y = wa * a.y + wb * b.y;
    o.z = wa * a.z + wb * b.z; o.w = wa * a.w + wb * b.w;
    *reinterpret_cast<float4*>(&out[(size_t)t * HD + c]) = o;
}

extern "C" void kernel_launch(void* const* d_in, const int* in_sizes, int n_in,
                              void* d_out, int out_size, void* d_ws, size_t ws_size,
                              hipStream_t stream) {
    const float* x  = (const float*)d_in[0];
    const float* rw = (const float*)d_in[1];
    const float* rb = (const float*)d_in[2];
    const float* w1 = (const float*)d_in[3];
    const float* b1 = (const float*)d_in[4];
    const float* w2 = (const float*)d_in[5];
    const float* b2 = (const float*)d_in[6];
    float* out = (float*)d_out;
    char* ws = (char*)d_ws;

    int*   counts  = (int*)(ws + OFF_COUNTS);
    int*   done    = (int*)(ws + OFF_DONE);
    int*   cursor  = (int*)(ws + OFF_CURSOR);
    int*   offs    = (int*)(ws + OFF_OFFS);
    int*   e0a     = (int*)(ws + OFF_E0);
    int*   e1a     = (int*)(ws + OFF_E1);
    float* w0a     = (float*)(ws + OFF_W0);
    float* w1a     = (float*)(ws + OFF_W1);
    int*   slot0   = (int*)(ws + OFF_S0);
    int*   slot1   = (int*)(ws + OFF_S1);
    int*   tid_arr = (int*)(ws + OFF_TID);
    float* tw_arr  = (float*)(ws + OFF_TW);
    int*   tmr     = (int*)(ws + OFF_TMR);
    int*   tme     = (int*)(ws + OFF_TME);
    int*   tmn     = (int*)(ws + OFF_TMN);
    bf16*  xbf     = (bf16*)(ws + OFF_XBF);
    bf16*  w1t     = (bf16*)(ws + OFF_W1T);
    bf16*  w2t     = (bf16*)(ws + OFF_W2T);
    bf16*  hmid    = (bf16*)(ws + OFF_HMID);
    float* ys      = (float*)(ws + OFF_YS);

    hipMemsetAsync(counts, 0, 64, stream);   // counts[0..7] + done

    fused1_kernel<<<4096, 256, 0, stream>>>(x, rw, rb, w1, xbf, w1t,
        e0a, e1a, w0a, w1a, counts, done, offs, cursor, tmr, tme, tmn);
    scatter_kernel<<<TT / 256, 256, 0, stream>>>(e0a, e1a, w0a, w1a, cursor,
        tid_arr, tw_arr, slot0, slot1);
    fused2_kernel<<<2048 + NWG1, 256, 0, stream>>>(w2, w2t, xbf, w1t, b1, offs,
        tid_arr, hmid, tmr, tme, tmn);
    gemm2_kernel<<<(HD / 128) * NTMAX, 256, 0, stream>>>(hmid, w2t, b2, offs, ys, tmr, tme, tmn);
    combine_kernel<<<TT, 256, 0, stream>>>(ys, slot0, slot1, tw_arr, out);
}

// Round 17
// 879.999 us; speedup vs baseline: 1.0867x; 1.0867x over previous
//
#include <hip/hip_runtime.h>
#include <hip/hip_bf16.h>
#include <math.h>

#define TT 8192
#define HD 1024
#define FHD 4096
#define NE 8
#define NTMAX 136
#define NWG1 4352

typedef short s16x8 __attribute__((ext_vector_type(8)));
typedef float f32x4 __attribute__((ext_vector_type(4)));
using bf16 = __hip_bfloat16;
typedef unsigned int u32;

// workspace layout (bytes)
#define OFF_COUNTS 0            // counts[0..7], done at +32
#define OFF_DONE   32
#define OFF_CURSOR 64
#define OFF_OFFS   128
#define OFF_E0     256
#define OFF_E1     (OFF_E0 + 4*TT)
#define OFF_W0     (OFF_E1 + 4*TT)
#define OFF_W1     (OFF_W0 + 4*TT)
#define OFF_S0     (OFF_W1 + 4*TT)
#define OFF_S1     (OFF_S0 + 4*TT)
#define OFF_TID    (OFF_S1 + 4*TT)
#define OFF_TW     (OFF_TID + 8*TT)
#define OFF_TMR    (OFF_TW + 8*TT)
#define OFF_TME    (OFF_TMR + 4*144)
#define OFF_TMN    (OFF_TME + 4*144)
#define OFF_XBF    (OFF_TMN + 64)
#define OFF_W1T    (OFF_XBF + 2*TT*HD)
#define OFF_W2T    (OFF_W1T + 2*NE*HD*FHD)
#define OFF_HMID   (OFF_W2T + 2*NE*HD*FHD)
#define OFF_YS     (OFF_HMID + (size_t)2*(2*TT)*FHD)

__device__ __forceinline__ void gload_lds16(const void* g, void* l) {
    __builtin_amdgcn_global_load_lds(
        (const __attribute__((address_space(1))) u32*)g,
        (__attribute__((address_space(3))) u32*)l, 16, 0, 0);
}

// transpose+cast one 256k x 64n panel (R9-proven), using caller's smem (50.4KB)
__device__ __forceinline__ void transpose_panel(const float* __restrict__ in,
        bf16* __restrict__ out, int R, int C, int rem, int tid, char* smem) {
    float (*tile)[65]  = reinterpret_cast<float(*)[65]>(smem);          // 16640 B
    bf16  (*btile)[264] = reinterpret_cast<bf16(*)[264]>(smem + 16640); // 33792 B
    int kch = R >> 8, nch = C >> 6;
    int per = kch * nch;
    int e = rem / per;
    int rem2 = rem % per;
    int kc = rem2 / nch, nc = rem2 % nch;
    int k0 = kc << 8, n0 = nc << 6;
    const float* ine = in + (size_t)e * R * C;
    bf16* oute = out + (size_t)e * R * C;
    for (int s = 0; s < 4; ++s) {
        int ks = k0 + s * 64;
#pragma unroll
        for (int i = 0; i < 4; ++i) {
            int lin = tid + i * 256;
            int r = lin >> 4, cg = lin & 15;
            float4 v = *reinterpret_cast<const float4*>(&ine[(size_t)(ks + r) * C + n0 + cg * 4]);
            tile[r][cg * 4 + 0] = v.x; tile[r][cg * 4 + 1] = v.y;
            tile[r][cg * 4 + 2] = v.z; tile[r][cg * 4 + 3] = v.w;
        }
        __syncthreads();
#pragma unroll
        for (int i = 0; i < 4; ++i) {
            int lin = tid + i * 256;
            int n = lin >> 4, kg = lin & 15;
            bf16 h[4];
            h[0] = __float2bfloat16(tile[kg * 4 + 0][n]);
            h[1] = __float2bfloat16(tile[kg * 4 + 1][n]);
            h[2] = __float2bfloat16(tile[kg * 4 + 2][n]);
            h[3] = __float2bfloat16(tile[kg * 4 + 3][n]);
            *reinterpret_cast<uint2*>(&btile[n][s * 64 + kg * 4]) = *reinterpret_cast<uint2*>(h);
        }
        __syncthreads();
    }
#pragma unroll
    for (int i = 0; i < 8; ++i) {
        int lin = tid + i * 256;
        int n = lin >> 5, kk = lin & 31;
        *reinterpret_cast<uint4*>(&oute[(size_t)(n0 + n) * R + k0 + kk * 8]) =
            *reinterpret_cast<const uint4*>(&btile[n][kk * 8]);
    }
}

// transpose+cast one 64x64 panel (R8-proven), small-LDS version (16.6KB)
__device__ __forceinline__ void transpose_panel64(const float* __restrict__ in,
        bf16* __restrict__ out, int R, int C, int rem, int tid, char* smem) {
    float (*tile)[65] = reinterpret_cast<float(*)[65]>(smem);
    int rt = R >> 6, ct = C >> 6;
    int per = rt * ct;
    int e = rem / per;
    int rem2 = rem % per;
    int r0 = (rem2 / ct) << 6, c0 = (rem2 % ct) << 6;
    const float* ine = in + (size_t)e * R * C;
    bf16* oute = out + (size_t)e * R * C;
#pragma unroll
    for (int i = 0; i < 4; ++i) {
        int lin = tid + i * 256;
        int r = lin >> 4, cg = lin & 15;
        float4 v = *reinterpret_cast<const float4*>(&ine[(size_t)(r0 + r) * C + c0 + cg * 4]);
        tile[r][cg * 4 + 0] = v.x; tile[r][cg * 4 + 1] = v.y;
        tile[r][cg * 4 + 2] = v.z; tile[r][cg * 4 + 3] = v.w;
    }
    __syncthreads();
#pragma unroll
    for (int i = 0; i < 4; ++i) {
        int lin = tid + i * 256;
        int n = lin >> 4, kg = lin & 15;
        bf16 h[4];
        h[0] = __float2bfloat16(tile[kg * 4 + 0][n]);
        h[1] = __float2bfloat16(tile[kg * 4 + 1][n]);
        h[2] = __float2bfloat16(tile[kg * 4 + 2][n]);
        h[3] = __float2bfloat16(tile[kg * 4 + 3][n]);
        *reinterpret_cast<uint2*>(&oute[(size_t)(c0 + n) * R + r0 + kg * 4]) =
            *reinterpret_cast<uint2*>(h);
    }
}

// ---------------- fused1: transpose w1 (blocks 0..2047) || router+cast+scan ----------------
__global__ __launch_bounds__(256) void fused1_kernel(
        const float* __restrict__ x, const float* __restrict__ rw, const float* __restrict__ rb,
        const float* __restrict__ w1, bf16* __restrict__ xbf, bf16* __restrict__ w1t,
        int* __restrict__ e0a, int* __restrict__ e1a,
        float* __restrict__ w0a, float* __restrict__ w1a,
        int* __restrict__ counts, int* __restrict__ done,
        int* __restrict__ offs, int* __restrict__ cursor,
        int* __restrict__ tmr, int* __restrict__ tme, int* __restrict__ tmn) {
    __shared__ __attribute__((aligned(16))) char smem[50432];
    int bid = blockIdx.x;
    int tid = threadIdx.x;
    if (bid < 2048) {
        transpose_panel(w1, w1t, HD, FHD, bid, tid, smem);
        return;
    }
    // ---- router (+cast) ----
    int rbid = bid - 2048;
    int wid = tid >> 6, lane = tid & 63;
    int t = rbid * 4 + wid;
    const float* xp = x + (size_t)t * HD + lane * 16;
    float xv[16];
#pragma unroll
    for (int j = 0; j < 4; ++j) {
        float4 v = *reinterpret_cast<const float4*>(&xp[j * 4]);
        xv[4 * j] = v.x; xv[4 * j + 1] = v.y; xv[4 * j + 2] = v.z; xv[4 * j + 3] = v.w;
    }
    {
        bf16 hv[16];
#pragma unroll
        for (int j = 0; j < 16; ++j) hv[j] = __float2bfloat16(xv[j]);
        uint4* dst = reinterpret_cast<uint4*>(&xbf[(size_t)t * HD + lane * 16]);
        dst[0] = reinterpret_cast<uint4*>(hv)[0];
        dst[1] = reinterpret_cast<uint4*>(hv)[1];
    }
    float acc[8] = {0.f, 0.f, 0.f, 0.f, 0.f, 0.f, 0.f, 0.f};
    const float* rp = rw + (size_t)(lane * 16) * NE;
#pragma unroll
    for (int hh = 0; hh < 16; ++hh) {
        float4 r0 = *reinterpret_cast<const float4*>(&rp[hh * 8]);
        float4 r1 = *reinterpret_cast<const float4*>(&rp[hh * 8 + 4]);
        acc[0] += xv[hh] * r0.x; acc[1] += xv[hh] * r0.y;
        acc[2] += xv[hh] * r0.z; acc[3] += xv[hh] * r0.w;
        acc[4] += xv[hh] * r1.x; acc[5] += xv[hh] * r1.y;
        acc[6] += xv[hh] * r1.z; acc[7] += xv[hh] * r1.w;
    }
#pragma unroll
    for (int e = 0; e < 8; ++e) {
#pragma unroll
        for (int off = 32; off > 0; off >>= 1) acc[e] += __shfl_xor(acc[e], off, 64);
    }
    if (lane == 0) {
        float lg[8];
#pragma unroll
        for (int e = 0; e < 8; ++e) lg[e] = acc[e] + rb[e];
        int a = 0;
#pragma unroll
        for (int e = 1; e < 8; ++e) if (lg[e] > lg[a]) a = e;
        int b = (a == 0) ? 1 : 0;
#pragma unroll
        for (int e = 0; e < 8; ++e) if (e != a && e != b && lg[e] > lg[b]) b = e;
        float wa = 1.0f / (1.0f + expf(lg[b] - lg[a]));
        float wb = 1.0f / (1.0f + expf(lg[a] - lg[b]));
        e0a[t] = a; e1a[t] = b; w0a[t] = wa; w1a[t] = wb;
        atomicAdd(&counts[a], 1);
        atomicAdd(&counts[b], 1);
    }
    __syncthreads();
    __shared__ int lastFlag;
    if (tid == 0) {
        __threadfence();
        lastFlag = (atomicAdd(done, 1) == 2047) ? 1 : 0;
    }
    __syncthreads();
    if (!lastFlag) return;
    __threadfence();
    __shared__ int cbase[NE + 1], tbase[NE + 1];
    if (tid == 0) {
        int s = 0, ntt = 0;
        for (int e = 0; e < NE; ++e) {
            int c = atomicAdd(&counts[e], 0);
            cbase[e] = s; tbase[e] = ntt;
            s += c; ntt += (c + 127) >> 7;
        }
        cbase[NE] = s; tbase[NE] = ntt;
        tmn[0] = ntt;
        offs[NE] = s;
    }
    __syncthreads();
    if (tid < NE) { offs[tid] = cbase[tid]; cursor[tid] = cbase[tid]; }
    if (tid < NTMAX) {
        int ntt = tbase[NE];
        if (tid < ntt) {
            int e = 0;
            while (tbase[e + 1] <= tid) ++e;
            tmr[tid] = cbase[e] + ((tid - tbase[e]) << 7);
            tme[tid] = e;
        } else { tmr[tid] = 0; tme[tid] = 0; }
    }
}

__global__ __launch_bounds__(256) void scatter_kernel(const int* __restrict__ e0a, const int* __restrict__ e1a,
        const float* __restrict__ w0a, const float* __restrict__ w1a,
        int* __restrict__ cursor, int* __restrict__ tid_arr, float* __restrict__ tw_arr,
        int* __restrict__ slot0, int* __restrict__ slot1) {
    int t = blockIdx.x * 256 + threadIdx.x;
    int s0 = atomicAdd(&cursor[e0a[t]], 1);
    tid_arr[s0] = t; tw_arr[s0] = w0a[t]; slot0[t] = s0;
    int s1 = atomicAdd(&cursor[e1a[t]], 1);
    tid_arr[s1] = t; tw_arr[s1] = w1a[t]; slot1[t] = s1;
}

// ---------------- fused2: interleaved {1 gemm1 : 2 transpose-w2(64x64)} ----------------
// Small LDS union (16.9KB) + launch_bounds(256,4): acc(64 AGPR)+64 VGPR = 128
// regs/wave -> 4 waves/SIMD (was 140 -> 3). Grid 13056 = 3*4352.
__global__ __launch_bounds__(256, 4) void fused2_kernel(
        const float* __restrict__ w2, bf16* __restrict__ w2t,
        const bf16* __restrict__ xbf, const bf16* __restrict__ w1t,
        const float* __restrict__ b1, const int* __restrict__ offs,
        const int* __restrict__ tid_arr, bf16* __restrict__ hmid,
        const int* __restrict__ tmr, const int* __restrict__ tme, const int* __restrict__ tmn) {
    __shared__ __attribute__((aligned(16))) char smem[16896];
    int bid = blockIdx.x;
    int tid = threadIdx.x;
    int q = bid % 3, h = bid / 3;
    if (q != 0) {
        int tpid = h * 2 + (q - 1);
        if (tpid < 8192) transpose_panel64(w2, w2t, FHD, HD, tpid, tid, smem);
        return;
    }
    // ---- gemm1 section (R14-verbatim structure) ----
    bf16* As = reinterpret_cast<bf16*>(smem);            // 8192 B
    bf16* Bs = reinterpret_cast<bf16*>(smem + 8192);     // 8192 B
    int*  toks = reinterpret_cast<int*>(smem + 16384);   // 512 B
    int orig = h;                          // 0..4351
    // XCD chunking for stride-3 placement: xcd = (3*h)&7
    int wg = (((3 * orig) & 7) * (NWG1 >> 3)) + (orig >> 3);
    int st = wg / 136, within = wg % 136;
    int tidx = (st >> 2) * 17 + (within % 17);
    int nt = (st & 3) * 8 + (within / 17);
    if (tidx >= tmn[0]) return;
    int e = tme[tidx];
    int row0 = tmr[tidx];
    int s1 = offs[e + 1];
    int n0 = nt * 128;
    if (tid < 128) { int s = row0 + tid; toks[tid] = tid_arr[(s < s1) ? s : (s1 - 1)]; }
    __syncthreads();
    int lane = tid & 63, w = tid >> 6;
    int wrow = (w >> 1) * 64, wcol = (w & 1) * 64;
    int lr = lane & 15, lk = (lane >> 4) * 8;
    int srow = lane >> 2, seg = lane & 3;
    int tokA0 = toks[w * 32 + srow];
    int tokA1 = toks[w * 32 + 16 + srow];
    const bf16* w1e = w1t + (size_t)e * FHD * HD;
    const bf16* bsrc0 = w1e + (size_t)(n0 + w * 32 + srow) * HD + seg * 8;
    const bf16* bsrc1 = w1e + (size_t)(n0 + w * 32 + 16 + srow) * HD + seg * 8;
    const bf16* asrc0 = xbf + (size_t)tokA0 * HD + seg * 8;
    const bf16* asrc1 = xbf + (size_t)tokA1 * HD + seg * 8;
    bf16* aDst0 = &As[(w * 32) * 32];
    bf16* aDst1 = &As[(w * 32 + 16) * 32];
    bf16* bDst0 = &Bs[(w * 32) * 32];
    bf16* bDst1 = &Bs[(w * 32 + 16) * 32];
    f32x4 acc[4][4] = {};
    for (int k0 = 0; k0 < HD; k0 += 32) {
        gload_lds16(asrc0 + k0, aDst0);
        gload_lds16(asrc1 + k0, aDst1);
        gload_lds16(bsrc0 + k0, bDst0);
        gload_lds16(bsrc1 + k0, bDst1);
        __syncthreads();
        s16x8 aF[4], bF[4];
#pragma unroll
        for (int m = 0; m < 4; ++m) aF[m] = *reinterpret_cast<const s16x8*>(&As[(wrow + m * 16 + lr) * 32 + lk]);
#pragma unroll
        for (int n = 0; n < 4; ++n) bF[n] = *reinterpret_cast<const s16x8*>(&Bs[(wcol + n * 16 + lr) * 32 + lk]);
#pragma unroll
        for (int m = 0; m < 4; ++m)
#pragma unroll
            for (int n = 0; n < 4; ++n)
                acc[m][n] = __builtin_amdgcn_mfma_f32_16x16x32_bf16(aF[m], bF[n], acc[m][n], 0, 0, 0);
        __syncthreads();
    }
#pragma unroll
    for (int m = 0; m < 4; ++m) {
#pragma unroll
        for (int n = 0; n < 4; ++n) {
            int col = n0 + wcol + n * 16 + lr;
            float bv = b1[(size_t)e * FHD + col];
#pragma unroll
            for (int r = 0; r < 4; ++r) {
                int row = wrow + m * 16 + (lane >> 4) * 4 + r;
                int slot = row0 + row;
                if (slot < s1) {
                    float v2 = acc[m][n][r] + bv;
                    v2 = 0.5f * v2 * (1.0f + erff(v2 * 0.70710678118f));
                    hmid[(size_t)slot * FHD + col] = __float2bfloat16(v2);
                }
            }
        }
    }
}

// GEMM2 with 2D supertile decode (17 tidx x 4 nt), launch_bounds(256,4)
__global__ __launch_bounds__(256, 4) void gemm2_kernel(const bf16* __restrict__ hmid, const bf16* __restrict__ w2t,
        const float* __restrict__ b2, const int* __restrict__ offs, float* __restrict__ ys,
        const int* __restrict__ tmr, const int* __restrict__ tme, const int* __restrict__ tmn) {
    __shared__ bf16 As[128 * 32];
    __shared__ bf16 Bs[128 * 32];
    int nwg = gridDim.x;              // 1088, %8==0
    int orig = blockIdx.x;
    int wg = (orig & 7) * (nwg >> 3) + (orig >> 3);
    int st = wg / 68, within = wg % 68;
    int tidx = (st >> 1) * 17 + (within % 17);
    int nt = (st & 1) * 4 + (within / 17);
    if (tidx >= tmn[0]) return;
    int e = tme[tidx];
    int row0 = tmr[tidx];
    int s1 = offs[e + 1];
    int n0 = nt * 128;
    int tid = threadIdx.x;
    int lane = tid & 63, w = tid >> 6;
    int wrow = (w >> 1) * 64, wcol = (w & 1) * 64;
    int lr = lane & 15, lk = (lane >> 4) * 8;
    int srow = lane >> 2, seg = lane & 3;
    int ar0 = row0 + w * 32 + srow;      if (ar0 >= s1) ar0 = s1 - 1;
    int ar1 = row0 + w * 32 + 16 + srow; if (ar1 >= s1) ar1 = s1 - 1;
    const bf16* w2e = w2t + (size_t)e * HD * FHD;
    const bf16* bsrc0 = w2e + (size_t)(n0 + w * 32 + srow) * FHD + seg * 8;
    const bf16* bsrc1 = w2e + (size_t)(n0 + w * 32 + 16 + srow) * FHD + seg * 8;
    const bf16* asrc0 = hmid + (size_t)ar0 * FHD + seg * 8;
    const bf16* asrc1 = hmid + (size_t)ar1 * FHD + seg * 8;
    bf16* aDst0 = &As[(w * 32) * 32];
    bf16* aDst1 = &As[(w * 32 + 16) * 32];
    bf16* bDst0 = &Bs[(w * 32) * 32];
    bf16* bDst1 = &Bs[(w * 32 + 16) * 32];
    f32x4 acc[4][4] = {};
    for (int k0 = 0; k0 < FHD; k0 += 32) {
        gload_lds16(asrc0 + k0, aDst0);
        gload_lds16(asrc1 + k0, aDst1);
        gload_lds16(bsrc0 + k0, bDst0);
        gload_lds16(bsrc1 + k0, bDst1);
        __syncthreads();
        s16x8 aF[4], bF[4];
#pragma unroll
        for (int m = 0; m < 4; ++m) aF[m] = *reinterpret_cast<const s16x8*>(&As[(wrow + m * 16 + lr) * 32 + lk]);
#pragma unroll
        for (int n = 0; n < 4; ++n) bF[n] = *reinterpret_cast<const s16x8*>(&Bs[(wcol + n * 16 + lr) * 32 + lk]);
#pragma unroll
        for (int m = 0; m < 4; ++m)
#pragma unroll
            for (int n = 0; n < 4; ++n)
                acc[m][n] = __builtin_amdgcn_mfma_f32_16x16x32_bf16(aF[m], bF[n], acc[m][n], 0, 0, 0);
        __syncthreads();
    }
#pragma unroll
    for (int m = 0; m < 4; ++m) {
#pragma unroll
        for (int n = 0; n < 4; ++n) {
            int col = n0 + wcol + n * 16 + lr;
            float bv = b2[(size_t)e * HD + col];
#pragma unroll
            for (int r = 0; r < 4; ++r) {
                int row = wrow + m * 16 + (lane >> 4) * 4 + r;
                int slot = row0 + row;
                if (slot < s1) ys[(size_t)slot * HD + col] = acc[m][n][r] + bv;
            }
        }
    }
}

// out[t,:] = tw[slot0[t]] * ys[slot0[t],:] + tw[slot1[t]] * ys[slot1[t],:]
__global__ __launch_bounds__(256) void combine_kernel(const float* __restrict__ ys,
        const int* __restrict__ slot0, const int* __restrict__ slot1,
        const float* __restrict__ tw, float* __restrict__ out) {
    int t = blockIdx.x;
    int c = threadIdx.x * 4;
    int sa = slot0[t], sb = slot1[t];
    float wa = tw[sa], wb = tw[sb];
    float4 a = *reinterpret_cast<const float4*>(&ys[(size_t)sa * HD + c]);
    float4 b = *reinterpret_cast<const float4*>(&ys[(size_t)sb * HD + c]);
    float4 o;
    o.x = wa * a.x + wb * b.x; o.y = wa * a.y + wb * b.y;
    o.z = wa * a.z + wb * b.z; o.w = wa * a.w + wb * b.w;
    *reinterpret_cast<float4*>(&out[(size_t)t * HD + c]) = o;
}

extern "C" void kernel_launch(void* const* d_in, const int* in_sizes, int n_in,
                              void* d_out, int out_size, void* d_ws, size_t ws_size,
                              hipStream_t stream) {
    const float* x  = (const float*)d_in[0];
    const float* rw = (const float*)d_in[1];
    const float* rb = (const float*)d_in[2];
    const float* w1 = (const float*)d_in[3];
    const float* b1 = (const float*)d_in[4];
    const float* w2 = (const float*)d_in[5];
    const float* b2 = (const float*)d_in[6];
    float* out = (float*)d_out;
    char* ws = (char*)d_ws;

    int*   counts  = (int*)(ws + OFF_COUNTS);
    int*   done    = (int*)(ws + OFF_DONE);
    int*   cursor  = (int*)(ws + OFF_CURSOR);
    int*   offs    = (int*)(ws + OFF_OFFS);
    int*   e0a     = (int*)(ws + OFF_E0);
    int*   e1a     = (int*)(ws + OFF_E1);
    float* w0a     = (float*)(ws + OFF_W0);
    float* w1a     = (float*)(ws + OFF_W1);
    int*   slot0   = (int*)(ws + OFF_S0);
    int*   slot1   = (int*)(ws + OFF_S1);
    int*   tid_arr = (int*)(ws + OFF_TID);
    float* tw_arr  = (float*)(ws + OFF_TW);
    int*   tmr     = (int*)(ws + OFF_TMR);
    int*   tme     = (int*)(ws + OFF_TME);
    int*   tmn     = (int*)(ws + OFF_TMN);
    bf16*  xbf     = (bf16*)(ws + OFF_XBF);
    bf16*  w1t     = (bf16*)(ws + OFF_W1T);
    bf16*  w2t     = (bf16*)(ws + OFF_W2T);
    bf16*  hmid    = (bf16*)(ws + OFF_HMID);
    float* ys      = (float*)(ws + OFF_YS);

    hipMemsetAsync(counts, 0, 64, stream);   // counts[0..7] + done

    fused1_kernel<<<4096, 256, 0, stream>>>(x, rw, rb, w1, xbf, w1t,
        e0a, e1a, w0a, w1a, counts, done, offs, cursor, tmr, tme, tmn);
    scatter_kernel<<<TT / 256, 256, 0, stream>>>(e0a, e1a, w0a, w1a, cursor,
        tid_arr, tw_arr, slot0, slot1);
    fused2_kernel<<<3 * NWG1, 256, 0, stream>>>(w2, w2t, xbf, w1t, b1, offs,
        tid_arr, hmid, tmr, tme, tmn);
    gemm2_kernel<<<(HD / 128) * NTMAX, 256, 0, stream>>>(hmid, w2t, b2, offs, ys, tmr, tme, tmn);
    combine_kernel<<<TT, 256, 0, stream>>>(ys, slot0, slot1, tw_arr, out);
}

// Round 18
// 858.253 us; speedup vs baseline: 1.1142x; 1.0253x over previous
//
#include <hip/hip_runtime.h>
#include <hip/hip_bf16.h>
#include <math.h>

#define TT 8192
#define HD 1024
#define FHD 4096
#define NE 8
#define NTMAX 136
#define NWG1 4352

typedef short s16x8 __attribute__((ext_vector_type(8)));
typedef float f32x4 __attribute__((ext_vector_type(4)));
using bf16 = __hip_bfloat16;
typedef unsigned int u32;

// workspace layout (bytes)
#define OFF_COUNTS 0            // counts[0..7], done at +32
#define OFF_DONE   32
#define OFF_CURSOR 64
#define OFF_OFFS   128
#define OFF_E0     256
#define OFF_E1     (OFF_E0 + 4*TT)
#define OFF_W0     (OFF_E1 + 4*TT)
#define OFF_W1     (OFF_W0 + 4*TT)
#define OFF_S0     (OFF_W1 + 4*TT)
#define OFF_S1     (OFF_S0 + 4*TT)
#define OFF_TID    (OFF_S1 + 4*TT)
#define OFF_TW     (OFF_TID + 8*TT)
#define OFF_TMR    (OFF_TW + 8*TT)
#define OFF_TME    (OFF_TMR + 4*144)
#define OFF_TMN    (OFF_TME + 4*144)
#define OFF_XBF    (OFF_TMN + 64)
#define OFF_W1T    (OFF_XBF + 2*TT*HD)
#define OFF_W2T    (OFF_W1T + 2*NE*HD*FHD)
#define OFF_HMID   (OFF_W2T + 2*NE*HD*FHD)
#define OFF_YS     (OFF_HMID + (size_t)2*(2*TT)*FHD)

__device__ __forceinline__ void gload_lds16(const void* g, void* l) {
    __builtin_amdgcn_global_load_lds(
        (const __attribute__((address_space(1))) u32*)g,
        (__attribute__((address_space(3))) u32*)l, 16, 0, 0);
}

// transpose+cast one 256k x 64n panel (R9-proven), using caller's smem (50.4KB)
__device__ __forceinline__ void transpose_panel(const float* __restrict__ in,
        bf16* __restrict__ out, int R, int C, int rem, int tid, char* smem) {
    float (*tile)[65]  = reinterpret_cast<float(*)[65]>(smem);          // 16640 B
    bf16  (*btile)[264] = reinterpret_cast<bf16(*)[264]>(smem + 16640); // 33792 B
    int kch = R >> 8, nch = C >> 6;
    int per = kch * nch;
    int e = rem / per;
    int rem2 = rem % per;
    int kc = rem2 / nch, nc = rem2 % nch;
    int k0 = kc << 8, n0 = nc << 6;
    const float* ine = in + (size_t)e * R * C;
    bf16* oute = out + (size_t)e * R * C;
    for (int s = 0; s < 4; ++s) {
        int ks = k0 + s * 64;
#pragma unroll
        for (int i = 0; i < 4; ++i) {
            int lin = tid + i * 256;
            int r = lin >> 4, cg = lin & 15;
            float4 v = *reinterpret_cast<const float4*>(&ine[(size_t)(ks + r) * C + n0 + cg * 4]);
            tile[r][cg * 4 + 0] = v.x; tile[r][cg * 4 + 1] = v.y;
            tile[r][cg * 4 + 2] = v.z; tile[r][cg * 4 + 3] = v.w;
        }
        __syncthreads();
#pragma unroll
        for (int i = 0; i < 4; ++i) {
            int lin = tid + i * 256;
            int n = lin >> 4, kg = lin & 15;
            bf16 h[4];
            h[0] = __float2bfloat16(tile[kg * 4 + 0][n]);
            h[1] = __float2bfloat16(tile[kg * 4 + 1][n]);
            h[2] = __float2bfloat16(tile[kg * 4 + 2][n]);
            h[3] = __float2bfloat16(tile[kg * 4 + 3][n]);
            *reinterpret_cast<uint2*>(&btile[n][s * 64 + kg * 4]) = *reinterpret_cast<uint2*>(h);
        }
        __syncthreads();
    }
#pragma unroll
    for (int i = 0; i < 8; ++i) {
        int lin = tid + i * 256;
        int n = lin >> 5, kk = lin & 31;
        *reinterpret_cast<uint4*>(&oute[(size_t)(n0 + n) * R + k0 + kk * 8]) =
            *reinterpret_cast<const uint4*>(&btile[n][kk * 8]);
    }
}

// transpose+cast one 64x64 panel (R8-proven), small-LDS version (16.6KB)
__device__ __forceinline__ void transpose_panel64(const float* __restrict__ in,
        bf16* __restrict__ out, int R, int C, int rem, int tid, char* smem) {
    float (*tile)[65] = reinterpret_cast<float(*)[65]>(smem);
    int rt = R >> 6, ct = C >> 6;
    int per = rt * ct;
    int e = rem / per;
    int rem2 = rem % per;
    int r0 = (rem2 / ct) << 6, c0 = (rem2 % ct) << 6;
    const float* ine = in + (size_t)e * R * C;
    bf16* oute = out + (size_t)e * R * C;
#pragma unroll
    for (int i = 0; i < 4; ++i) {
        int lin = tid + i * 256;
        int r = lin >> 4, cg = lin & 15;
        float4 v = *reinterpret_cast<const float4*>(&ine[(size_t)(r0 + r) * C + c0 + cg * 4]);
        tile[r][cg * 4 + 0] = v.x; tile[r][cg * 4 + 1] = v.y;
        tile[r][cg * 4 + 2] = v.z; tile[r][cg * 4 + 3] = v.w;
    }
    __syncthreads();
#pragma unroll
    for (int i = 0; i < 4; ++i) {
        int lin = tid + i * 256;
        int n = lin >> 4, kg = lin & 15;
        bf16 h[4];
        h[0] = __float2bfloat16(tile[kg * 4 + 0][n]);
        h[1] = __float2bfloat16(tile[kg * 4 + 1][n]);
        h[2] = __float2bfloat16(tile[kg * 4 + 2][n]);
        h[3] = __float2bfloat16(tile[kg * 4 + 3][n]);
        *reinterpret_cast<uint2*>(&oute[(size_t)(c0 + n) * R + r0 + kg * 4]) =
            *reinterpret_cast<uint2*>(h);
    }
}

// ---------------- fused1: transpose w1 (blocks 0..2047) || router+cast+scan ----------------
__global__ __launch_bounds__(256) void fused1_kernel(
        const float* __restrict__ x, const float* __restrict__ rw, const float* __restrict__ rb,
        const float* __restrict__ w1, bf16* __restrict__ xbf, bf16* __restrict__ w1t,
        int* __restrict__ e0a, int* __restrict__ e1a,
        float* __restrict__ w0a, float* __restrict__ w1a,
        int* __restrict__ counts, int* __restrict__ done,
        int* __restrict__ offs, int* __restrict__ cursor,
        int* __restrict__ tmr, int* __restrict__ tme, int* __restrict__ tmn) {
    __shared__ __attribute__((aligned(16))) char smem[50432];
    int bid = blockIdx.x;
    int tid = threadIdx.x;
    if (bid < 2048) {
        transpose_panel(w1, w1t, HD, FHD, bid, tid, smem);
        return;
    }
    // ---- router (+cast) ----
    int rbid = bid - 2048;
    int wid = tid >> 6, lane = tid & 63;
    int t = rbid * 4 + wid;
    const float* xp = x + (size_t)t * HD + lane * 16;
    float xv[16];
#pragma unroll
    for (int j = 0; j < 4; ++j) {
        float4 v = *reinterpret_cast<const float4*>(&xp[j * 4]);
        xv[4 * j] = v.x; xv[4 * j + 1] = v.y; xv[4 * j + 2] = v.z; xv[4 * j + 3] = v.w;
    }
    {
        bf16 hv[16];
#pragma unroll
        for (int j = 0; j < 16; ++j) hv[j] = __float2bfloat16(xv[j]);
        uint4* dst = reinterpret_cast<uint4*>(&xbf[(size_t)t * HD + lane * 16]);
        dst[0] = reinterpret_cast<uint4*>(hv)[0];
        dst[1] = reinterpret_cast<uint4*>(hv)[1];
    }
    float acc[8] = {0.f, 0.f, 0.f, 0.f, 0.f, 0.f, 0.f, 0.f};
    const float* rp = rw + (size_t)(lane * 16) * NE;
#pragma unroll
    for (int hh = 0; hh < 16; ++hh) {
        float4 r0 = *reinterpret_cast<const float4*>(&rp[hh * 8]);
        float4 r1 = *reinterpret_cast<const float4*>(&rp[hh * 8 + 4]);
        acc[0] += xv[hh] * r0.x; acc[1] += xv[hh] * r0.y;
        acc[2] += xv[hh] * r0.z; acc[3] += xv[hh] * r0.w;
        acc[4] += xv[hh] * r1.x; acc[5] += xv[hh] * r1.y;
        acc[6] += xv[hh] * r1.z; acc[7] += xv[hh] * r1.w;
    }
#pragma unroll
    for (int e = 0; e < 8; ++e) {
#pragma unroll
        for (int off = 32; off > 0; off >>= 1) acc[e] += __shfl_xor(acc[e], off, 64);
    }
    if (lane == 0) {
        float lg[8];
#pragma unroll
        for (int e = 0; e < 8; ++e) lg[e] = acc[e] + rb[e];
        int a = 0;
#pragma unroll
        for (int e = 1; e < 8; ++e) if (lg[e] > lg[a]) a = e;
        int b = (a == 0) ? 1 : 0;
#pragma unroll
        for (int e = 0; e < 8; ++e) if (e != a && e != b && lg[e] > lg[b]) b = e;
        float wa = 1.0f / (1.0f + expf(lg[b] - lg[a]));
        float wb = 1.0f / (1.0f + expf(lg[a] - lg[b]));
        e0a[t] = a; e1a[t] = b; w0a[t] = wa; w1a[t] = wb;
        atomicAdd(&counts[a], 1);
        atomicAdd(&counts[b], 1);
    }
    __syncthreads();
    __shared__ int lastFlag;
    if (tid == 0) {
        __threadfence();
        lastFlag = (atomicAdd(done, 1) == 2047) ? 1 : 0;
    }
    __syncthreads();
    if (!lastFlag) return;
    __threadfence();
    __shared__ int cbase[NE + 1], tbase[NE + 1];
    if (tid == 0) {
        int s = 0, ntt = 0;
        for (int e = 0; e < NE; ++e) {
            int c = atomicAdd(&counts[e], 0);
            cbase[e] = s; tbase[e] = ntt;
            s += c; ntt += (c + 127) >> 7;
        }
        cbase[NE] = s; tbase[NE] = ntt;
        tmn[0] = ntt;
        offs[NE] = s;
    }
    __syncthreads();
    if (tid < NE) { offs[tid] = cbase[tid]; cursor[tid] = cbase[tid]; }
    if (tid < NTMAX) {
        int ntt = tbase[NE];
        if (tid < ntt) {
            int e = 0;
            while (tbase[e + 1] <= tid) ++e;
            tmr[tid] = cbase[e] + ((tid - tbase[e]) << 7);
            tme[tid] = e;
        } else { tmr[tid] = 0; tme[tid] = 0; }
    }
}

__global__ __launch_bounds__(256) void scatter_kernel(const int* __restrict__ e0a, const int* __restrict__ e1a,
        const float* __restrict__ w0a, const float* __restrict__ w1a,
        int* __restrict__ cursor, int* __restrict__ tid_arr, float* __restrict__ tw_arr,
        int* __restrict__ slot0, int* __restrict__ slot1) {
    int t = blockIdx.x * 256 + threadIdx.x;
    int s0 = atomicAdd(&cursor[e0a[t]], 1);
    tid_arr[s0] = t; tw_arr[s0] = w0a[t]; slot0[t] = s0;
    int s1 = atomicAdd(&cursor[e1a[t]], 1);
    tid_arr[s1] = t; tw_arr[s1] = w1a[t]; slot1[t] = s1;
}

// ---------------- fused2: interleaved {1 gemm1 : 2 transpose-w2(64x64)} ----------------
__global__ __launch_bounds__(256, 4) void fused2_kernel(
        const float* __restrict__ w2, bf16* __restrict__ w2t,
        const bf16* __restrict__ xbf, const bf16* __restrict__ w1t,
        const float* __restrict__ b1, const int* __restrict__ offs,
        const int* __restrict__ tid_arr, bf16* __restrict__ hmid,
        const int* __restrict__ tmr, const int* __restrict__ tme, const int* __restrict__ tmn) {
    __shared__ __attribute__((aligned(16))) char smem[16896];
    int bid = blockIdx.x;
    int tid = threadIdx.x;
    int q = bid % 3, h = bid / 3;
    if (q != 0) {
        int tpid = h * 2 + (q - 1);
        if (tpid < 8192) transpose_panel64(w2, w2t, FHD, HD, tpid, tid, smem);
        return;
    }
    // ---- gemm1 section (R14-verbatim structure) ----
    bf16* As = reinterpret_cast<bf16*>(smem);            // 8192 B
    bf16* Bs = reinterpret_cast<bf16*>(smem + 8192);     // 8192 B
    int*  toks = reinterpret_cast<int*>(smem + 16384);   // 512 B
    int orig = h;                          // 0..4351
    int wg = (((3 * orig) & 7) * (NWG1 >> 3)) + (orig >> 3);
    int st = wg / 136, within = wg % 136;
    int tidx = (st >> 2) * 17 + (within % 17);
    int nt = (st & 3) * 8 + (within / 17);
    if (tidx >= tmn[0]) return;
    int e = tme[tidx];
    int row0 = tmr[tidx];
    int s1 = offs[e + 1];
    int n0 = nt * 128;
    if (tid < 128) { int s = row0 + tid; toks[tid] = tid_arr[(s < s1) ? s : (s1 - 1)]; }
    __syncthreads();
    int lane = tid & 63, w = tid >> 6;
    int wrow = (w >> 1) * 64, wcol = (w & 1) * 64;
    int lr = lane & 15, lk = (lane >> 4) * 8;
    int srow = lane >> 2, seg = lane & 3;
    int tokA0 = toks[w * 32 + srow];
    int tokA1 = toks[w * 32 + 16 + srow];
    const bf16* w1e = w1t + (size_t)e * FHD * HD;
    const bf16* bsrc0 = w1e + (size_t)(n0 + w * 32 + srow) * HD + seg * 8;
    const bf16* bsrc1 = w1e + (size_t)(n0 + w * 32 + 16 + srow) * HD + seg * 8;
    const bf16* asrc0 = xbf + (size_t)tokA0 * HD + seg * 8;
    const bf16* asrc1 = xbf + (size_t)tokA1 * HD + seg * 8;
    bf16* aDst0 = &As[(w * 32) * 32];
    bf16* aDst1 = &As[(w * 32 + 16) * 32];
    bf16* bDst0 = &Bs[(w * 32) * 32];
    bf16* bDst1 = &Bs[(w * 32 + 16) * 32];
    f32x4 acc[4][4] = {};
    for (int k0 = 0; k0 < HD; k0 += 32) {
        gload_lds16(asrc0 + k0, aDst0);
        gload_lds16(asrc1 + k0, aDst1);
        gload_lds16(bsrc0 + k0, bDst0);
        gload_lds16(bsrc1 + k0, bDst1);
        __syncthreads();
        s16x8 aF[4], bF[4];
#pragma unroll
        for (int m = 0; m < 4; ++m) aF[m] = *reinterpret_cast<const s16x8*>(&As[(wrow + m * 16 + lr) * 32 + lk]);
#pragma unroll
        for (int n = 0; n < 4; ++n) bF[n] = *reinterpret_cast<const s16x8*>(&Bs[(wcol + n * 16 + lr) * 32 + lk]);
#pragma unroll
        for (int m = 0; m < 4; ++m)
#pragma unroll
            for (int n = 0; n < 4; ++n)
                acc[m][n] = __builtin_amdgcn_mfma_f32_16x16x32_bf16(aF[m], bF[n], acc[m][n], 0, 0, 0);
        __syncthreads();
    }
#pragma unroll
    for (int m = 0; m < 4; ++m) {
#pragma unroll
        for (int n = 0; n < 4; ++n) {
            int col = n0 + wcol + n * 16 + lr;
            float bv = b1[(size_t)e * FHD + col];
#pragma unroll
            for (int r = 0; r < 4; ++r) {
                int row = wrow + m * 16 + (lane >> 4) * 4 + r;
                int slot = row0 + row;
                if (slot < s1) {
                    float v2 = acc[m][n][r] + bv;
                    v2 = 0.5f * v2 * (1.0f + erff(v2 * 0.70710678118f));
                    hmid[(size_t)slot * FHD + col] = __float2bfloat16(v2);
                }
            }
        }
    }
}

// GEMM2 with 2D supertile decode (17 tidx x 4 nt), bf16 ys output
__global__ __launch_bounds__(256, 4) void gemm2_kernel(const bf16* __restrict__ hmid, const bf16* __restrict__ w2t,
        const float* __restrict__ b2, const int* __restrict__ offs, bf16* __restrict__ ys,
        const int* __restrict__ tmr, const int* __restrict__ tme, const int* __restrict__ tmn) {
    __shared__ bf16 As[128 * 32];
    __shared__ bf16 Bs[128 * 32];
    int nwg = gridDim.x;              // 1088, %8==0
    int orig = blockIdx.x;
    int wg = (orig & 7) * (nwg >> 3) + (orig >> 3);
    int st = wg / 68, within = wg % 68;
    int tidx = (st >> 1) * 17 + (within % 17);
    int nt = (st & 1) * 4 + (within / 17);
    if (tidx >= tmn[0]) return;
    int e = tme[tidx];
    int row0 = tmr[tidx];
    int s1 = offs[e + 1];
    int n0 = nt * 128;
    int tid = threadIdx.x;
    int lane = tid & 63, w = tid >> 6;
    int wrow = (w >> 1) * 64, wcol = (w & 1) * 64;
    int lr = lane & 15, lk = (lane >> 4) * 8;
    int srow = lane >> 2, seg = lane & 3;
    int ar0 = row0 + w * 32 + srow;      if (ar0 >= s1) ar0 = s1 - 1;
    int ar1 = row0 + w * 32 + 16 + srow; if (ar1 >= s1) ar1 = s1 - 1;
    const bf16* w2e = w2t + (size_t)e * HD * FHD;
    const bf16* bsrc0 = w2e + (size_t)(n0 + w * 32 + srow) * FHD + seg * 8;
    const bf16* bsrc1 = w2e + (size_t)(n0 + w * 32 + 16 + srow) * FHD + seg * 8;
    const bf16* asrc0 = hmid + (size_t)ar0 * FHD + seg * 8;
    const bf16* asrc1 = hmid + (size_t)ar1 * FHD + seg * 8;
    bf16* aDst0 = &As[(w * 32) * 32];
    bf16* aDst1 = &As[(w * 32 + 16) * 32];
    bf16* bDst0 = &Bs[(w * 32) * 32];
    bf16* bDst1 = &Bs[(w * 32 + 16) * 32];
    f32x4 acc[4][4] = {};
    for (int k0 = 0; k0 < FHD; k0 += 32) {
        gload_lds16(asrc0 + k0, aDst0);
        gload_lds16(asrc1 + k0, aDst1);
        gload_lds16(bsrc0 + k0, bDst0);
        gload_lds16(bsrc1 + k0, bDst1);
        __syncthreads();
        s16x8 aF[4], bF[4];
#pragma unroll
        for (int m = 0; m < 4; ++m) aF[m] = *reinterpret_cast<const s16x8*>(&As[(wrow + m * 16 + lr) * 32 + lk]);
#pragma unroll
        for (int n = 0; n < 4; ++n) bF[n] = *reinterpret_cast<const s16x8*>(&Bs[(wcol + n * 16 + lr) * 32 + lk]);
#pragma unroll
        for (int m = 0; m < 4; ++m)
#pragma unroll
            for (int n = 0; n < 4; ++n)
                acc[m][n] = __builtin_amdgcn_mfma_f32_16x16x32_bf16(aF[m], bF[n], acc[m][n], 0, 0, 0);
        __syncthreads();
    }
#pragma unroll
    for (int m = 0; m < 4; ++m) {
#pragma unroll
        for (int n = 0; n < 4; ++n) {
            int col = n0 + wcol + n * 16 + lr;
            float bv = b2[(size_t)e * HD + col];
#pragma unroll
            for (int r = 0; r < 4; ++r) {
                int row = wrow + m * 16 + (lane >> 4) * 4 + r;
                int slot = row0 + row;
                if (slot < s1) ys[(size_t)slot * HD + col] = __float2bfloat16(acc[m][n][r] + bv);
            }
        }
    }
}

// out[t,:] = tw[slot0[t]] * ys[slot0[t],:] + tw[slot1[t]] * ys[slot1[t],:]  (ys bf16)
__global__ __launch_bounds__(256) void combine_kernel(const bf16* __restrict__ ys,
        const int* __restrict__ slot0, const int* __restrict__ slot1,
        const float* __restrict__ tw, float* __restrict__ out) {
    int t = blockIdx.x;
    int c = threadIdx.x * 4;
    int sa = slot0[t], sb = slot1[t];
    float wa = tw[sa], wb = tw[sb];
    uint2 araw = *reinterpret_cast<const uint2*>(&ys[(size_t)sa * HD + c]);
    uint2 braw = *reinterpret_cast<const uint2*>(&ys[(size_t)sb * HD + c]);
    const bf16* ab = reinterpret_cast<const bf16*>(&araw);
    const bf16* bb = reinterpret_cast<const bf16*>(&braw);
    float4 o;
    o.x = wa * __bfloat162float(ab[0]) + wb * __bfloat162float(bb[0]);
    o.y = wa * __bfloat162float(ab[1]) + wb * __bfloat162float(bb[1]);
    o.z = wa * __bfloat162float(ab[2]) + wb * __bfloat162float(bb[2]);
    o.w = wa * __bfloat162float(ab[3]) + wb * __bfloat162float(bb[3]);
    *reinterpret_cast<float4*>(&out[(size_t)t * HD + c]) = o;
}

extern "C" void kernel_launch(void* const* d_in, const int* in_sizes, int n_in,
                              void* d_out, int out_size, void* d_ws, size_t ws_size,
                              hipStream_t stream) {
    const float* x  = (const float*)d_in[0];
    const float* rw = (const float*)d_in[1];
    const float* rb = (const float*)d_in[2];
    const float* w1 = (const float*)d_in[3];
    const float* b1 = (const float*)d_in[4];
    const float* w2 = (const float*)d_in[5];
    const float* b2 = (const float*)d_in[6];
    float* out = (float*)d_out;
    char* ws = (char*)d_ws;

    int*   counts  = (int*)(ws + OFF_COUNTS);
    int*   done    = (int*)(ws + OFF_DONE);
    int*   cursor  = (int*)(ws + OFF_CURSOR);
    int*   offs    = (int*)(ws + OFF_OFFS);
    int*   e0a     = (int*)(ws + OFF_E0);
    int*   e1a     = (int*)(ws + OFF_E1);
    float* w0a     = (float*)(ws + OFF_W0);
    float* w1a     = (float*)(ws + OFF_W1);
    int*   slot0   = (int*)(ws + OFF_S0);
    int*   slot1   = (int*)(ws + OFF_S1);
    int*   tid_arr = (int*)(ws + OFF_TID);
    float* tw_arr  = (float*)(ws + OFF_TW);
    int*   tmr     = (int*)(ws + OFF_TMR);
    int*   tme     = (int*)(ws + OFF_TME);
    int*   tmn     = (int*)(ws + OFF_TMN);
    bf16*  xbf     = (bf16*)(ws + OFF_XBF);
    bf16*  w1t     = (bf16*)(ws + OFF_W1T);
    bf16*  w2t     = (bf16*)(ws + OFF_W2T);
    bf16*  hmid    = (bf16*)(ws + OFF_HMID);
    bf16*  ys      = (bf16*)(ws + OFF_YS);

    hipMemsetAsync(counts, 0, 64, stream);   // counts[0..7] + done

    fused1_kernel<<<4096, 256, 0, stream>>>(x, rw, rb, w1, xbf, w1t,
        e0a, e1a, w0a, w1a, counts, done, offs, cursor, tmr, tme, tmn);
    scatter_kernel<<<TT / 256, 256, 0, stream>>>(e0a, e1a, w0a, w1a, cursor,
        tid_arr, tw_arr, slot0, slot1);
    fused2_kernel<<<3 * NWG1, 256, 0, stream>>>(w2, w2t, xbf, w1t, b1, offs,
        tid_arr, hmid, tmr, tme, tmn);
    gemm2_kernel<<<(HD / 128) * NTMAX, 256, 0, stream>>>(hmid, w2t, b2, offs, ys, tmr, tme, tmn);
    combine_kernel<<<TT, 256, 0, stream>>>(ys, slot0, slot1, tw_arr, out);
}

// Round 19
// 858.076 us; speedup vs baseline: 1.1144x; 1.0002x over previous
//
#include <hip/hip_runtime.h>
#include <hip/hip_bf16.h>
#include <math.h>

#define TT 8192
#define HD 1024
#define FHD 4096
#define NE 8
#define NTMAX 136
#define NWG1 4352

typedef short s16x8 __attribute__((ext_vector_type(8)));
typedef float f32x4 __attribute__((ext_vector_type(4)));
using bf16 = __hip_bfloat16;
typedef unsigned int u32;

// workspace layout (bytes)
#define OFF_COUNTS 0            // counts[0..7], done at +32
#define OFF_DONE   32
#define OFF_CURSOR 64
#define OFF_OFFS   128
#define OFF_E0     256
#define OFF_E1     (OFF_E0 + 4*TT)
#define OFF_W0     (OFF_E1 + 4*TT)
#define OFF_W1     (OFF_W0 + 4*TT)
#define OFF_S0     (OFF_W1 + 4*TT)
#define OFF_S1     (OFF_S0 + 4*TT)
#define OFF_TID    (OFF_S1 + 4*TT)
#define OFF_TW     (OFF_TID + 8*TT)
#define OFF_TMR    (OFF_TW + 8*TT)
#define OFF_TME    (OFF_TMR + 4*144)
#define OFF_TMN    (OFF_TME + 4*144)
#define OFF_XBF    (OFF_TMN + 64)
#define OFF_W1T    (OFF_XBF + 2*TT*HD)
#define OFF_W2T    (OFF_W1T + 2*NE*HD*FHD)
#define OFF_HMID   (OFF_W2T + 2*NE*HD*FHD)
#define OFF_YS     (OFF_HMID + (size_t)2*(2*TT)*FHD)

__device__ __forceinline__ void gload_lds16(const void* g, void* l) {
    __builtin_amdgcn_global_load_lds(
        (const __attribute__((address_space(1))) u32*)g,
        (__attribute__((address_space(3))) u32*)l, 16, 0, 0);
}

// transpose+cast one 256k x 64n panel (R9-proven), using caller's smem (50.4KB)
__device__ __forceinline__ void transpose_panel(const float* __restrict__ in,
        bf16* __restrict__ out, int R, int C, int rem, int tid, char* smem) {
    float (*tile)[65]  = reinterpret_cast<float(*)[65]>(smem);          // 16640 B
    bf16  (*btile)[264] = reinterpret_cast<bf16(*)[264]>(smem + 16640); // 33792 B
    int kch = R >> 8, nch = C >> 6;
    int per = kch * nch;
    int e = rem / per;
    int rem2 = rem % per;
    int kc = rem2 / nch, nc = rem2 % nch;
    int k0 = kc << 8, n0 = nc << 6;
    const float* ine = in + (size_t)e * R * C;
    bf16* oute = out + (size_t)e * R * C;
    for (int s = 0; s < 4; ++s) {
        int ks = k0 + s * 64;
#pragma unroll
        for (int i = 0; i < 4; ++i) {
            int lin = tid + i * 256;
            int r = lin >> 4, cg = lin & 15;
            float4 v = *reinterpret_cast<const float4*>(&ine[(size_t)(ks + r) * C + n0 + cg * 4]);
            tile[r][cg * 4 + 0] = v.x; tile[r][cg * 4 + 1] = v.y;
            tile[r][cg * 4 + 2] = v.z; tile[r][cg * 4 + 3] = v.w;
        }
        __syncthreads();
#pragma unroll
        for (int i = 0; i < 4; ++i) {
            int lin = tid + i * 256;
            int n = lin >> 4, kg = lin & 15;
            bf16 h[4];
            h[0] = __float2bfloat16(tile[kg * 4 + 0][n]);
            h[1] = __float2bfloat16(tile[kg * 4 + 1][n]);
            h[2] = __float2bfloat16(tile[kg * 4 + 2][n]);
            h[3] = __float2bfloat16(tile[kg * 4 + 3][n]);
            *reinterpret_cast<uint2*>(&btile[n][s * 64 + kg * 4]) = *reinterpret_cast<uint2*>(h);
        }
        __syncthreads();
    }
#pragma unroll
    for (int i = 0; i < 8; ++i) {
        int lin = tid + i * 256;
        int n = lin >> 5, kk = lin & 31;
        *reinterpret_cast<uint4*>(&oute[(size_t)(n0 + n) * R + k0 + kk * 8]) =
            *reinterpret_cast<const uint4*>(&btile[n][kk * 8]);
    }
}

// transpose+cast one 64x64 panel (R8-proven), small-LDS version (16.6KB)
__device__ __forceinline__ void transpose_panel64(const float* __restrict__ in,
        bf16* __restrict__ out, int R, int C, int rem, int tid, char* smem) {
    float (*tile)[65] = reinterpret_cast<float(*)[65]>(smem);
    int rt = R >> 6, ct = C >> 6;
    int per = rt * ct;
    int e = rem / per;
    int rem2 = rem % per;
    int r0 = (rem2 / ct) << 6, c0 = (rem2 % ct) << 6;
    const float* ine = in + (size_t)e * R * C;
    bf16* oute = out + (size_t)e * R * C;
#pragma unroll
    for (int i = 0; i < 4; ++i) {
        int lin = tid + i * 256;
        int r = lin >> 4, cg = lin & 15;
        float4 v = *reinterpret_cast<const float4*>(&ine[(size_t)(r0 + r) * C + c0 + cg * 4]);
        tile[r][cg * 4 + 0] = v.x; tile[r][cg * 4 + 1] = v.y;
        tile[r][cg * 4 + 2] = v.z; tile[r][cg * 4 + 3] = v.w;
    }
    __syncthreads();
#pragma unroll
    for (int i = 0; i < 4; ++i) {
        int lin = tid + i * 256;
        int n = lin >> 4, kg = lin & 15;
        bf16 h[4];
        h[0] = __float2bfloat16(tile[kg * 4 + 0][n]);
        h[1] = __float2bfloat16(tile[kg * 4 + 1][n]);
        h[2] = __float2bfloat16(tile[kg * 4 + 2][n]);
        h[3] = __float2bfloat16(tile[kg * 4 + 3][n]);
        *reinterpret_cast<uint2*>(&oute[(size_t)(c0 + n) * R + r0 + kg * 4]) =
            *reinterpret_cast<uint2*>(h);
    }
}

// ---------------- fused1: transpose w1 (blocks 0..2047) || router+cast+scan ----------------
__global__ __launch_bounds__(256) void fused1_kernel(
        const float* __restrict__ x, const float* __restrict__ rw, const float* __restrict__ rb,
        const float* __restrict__ w1, bf16* __restrict__ xbf, bf16* __restrict__ w1t,
        int* __restrict__ e0a, int* __restrict__ e1a,
        float* __restrict__ w0a, float* __restrict__ w1a,
        int* __restrict__ counts, int* __restrict__ done,
        int* __restrict__ offs, int* __restrict__ cursor,
        int* __restrict__ tmr, int* __restrict__ tme, int* __restrict__ tmn) {
    __shared__ __attribute__((aligned(16))) char smem[50432];
    int bid = blockIdx.x;
    int tid = threadIdx.x;
    if (bid < 2048) {
        transpose_panel(w1, w1t, HD, FHD, bid, tid, smem);
        return;
    }
    // ---- router (+cast) ----
    int rbid = bid - 2048;
    int wid = tid >> 6, lane = tid & 63;
    int t = rbid * 4 + wid;
    const float* xp = x + (size_t)t * HD + lane * 16;
    float xv[16];
#pragma unroll
    for (int j = 0; j < 4; ++j) {
        float4 v = *reinterpret_cast<const float4*>(&xp[j * 4]);
        xv[4 * j] = v.x; xv[4 * j + 1] = v.y; xv[4 * j + 2] = v.z; xv[4 * j + 3] = v.w;
    }
    {
        bf16 hv[16];
#pragma unroll
        for (int j = 0; j < 16; ++j) hv[j] = __float2bfloat16(xv[j]);
        uint4* dst = reinterpret_cast<uint4*>(&xbf[(size_t)t * HD + lane * 16]);
        dst[0] = reinterpret_cast<uint4*>(hv)[0];
        dst[1] = reinterpret_cast<uint4*>(hv)[1];
    }
    float acc[8] = {0.f, 0.f, 0.f, 0.f, 0.f, 0.f, 0.f, 0.f};
    const float* rp = rw + (size_t)(lane * 16) * NE;
#pragma unroll
    for (int hh = 0; hh < 16; ++hh) {
        float4 r0 = *reinterpret_cast<const float4*>(&rp[hh * 8]);
        float4 r1 = *reinterpret_cast<const float4*>(&rp[hh * 8 + 4]);
        acc[0] += xv[hh] * r0.x; acc[1] += xv[hh] * r0.y;
        acc[2] += xv[hh] * r0.z; acc[3] += xv[hh] * r0.w;
        acc[4] += xv[hh] * r1.x; acc[5] += xv[hh] * r1.y;
        acc[6] += xv[hh] * r1.z; acc[7] += xv[hh] * r1.w;
    }
#pragma unroll
    for (int e = 0; e < 8; ++e) {
#pragma unroll
        for (int off = 32; off > 0; off >>= 1) acc[e] += __shfl_xor(acc[e], off, 64);
    }
    if (lane == 0) {
        float lg[8];
#pragma unroll
        for (int e = 0; e < 8; ++e) lg[e] = acc[e] + rb[e];
        int a = 0;
#pragma unroll
        for (int e = 1; e < 8; ++e) if (lg[e] > lg[a]) a = e;
        int b = (a == 0) ? 1 : 0;
#pragma unroll
        for (int e = 0; e < 8; ++e) if (e != a && e != b && lg[e] > lg[b]) b = e;
        float wa = 1.0f / (1.0f + expf(lg[b] - lg[a]));
        float wb = 1.0f / (1.0f + expf(lg[a] - lg[b]));
        e0a[t] = a; e1a[t] = b; w0a[t] = wa; w1a[t] = wb;
        atomicAdd(&counts[a], 1);
        atomicAdd(&counts[b], 1);
    }
    __syncthreads();
    __shared__ int lastFlag;
    if (tid == 0) {
        __threadfence();
        lastFlag = (atomicAdd(done, 1) == 2047) ? 1 : 0;
    }
    __syncthreads();
    if (!lastFlag) return;
    __threadfence();
    __shared__ int cbase[NE + 1], tbase[NE + 1];
    if (tid == 0) {
        int s = 0, ntt = 0;
        for (int e = 0; e < NE; ++e) {
            int c = atomicAdd(&counts[e], 0);
            cbase[e] = s; tbase[e] = ntt;
            s += c; ntt += (c + 127) >> 7;
        }
        cbase[NE] = s; tbase[NE] = ntt;
        tmn[0] = ntt;
        offs[NE] = s;
    }
    __syncthreads();
    if (tid < NE) { offs[tid] = cbase[tid]; cursor[tid] = cbase[tid]; }
    if (tid < NTMAX) {
        int ntt = tbase[NE];
        if (tid < ntt) {
            int e = 0;
            while (tbase[e + 1] <= tid) ++e;
            tmr[tid] = cbase[e] + ((tid - tbase[e]) << 7);
            tme[tid] = e;
        } else { tmr[tid] = 0; tme[tid] = 0; }
    }
}

__global__ __launch_bounds__(256) void scatter_kernel(const int* __restrict__ e0a, const int* __restrict__ e1a,
        const float* __restrict__ w0a, const float* __restrict__ w1a,
        int* __restrict__ cursor, int* __restrict__ tid_arr, float* __restrict__ tw_arr,
        int* __restrict__ slot0, int* __restrict__ slot1) {
    int t = blockIdx.x * 256 + threadIdx.x;
    int s0 = atomicAdd(&cursor[e0a[t]], 1);
    tid_arr[s0] = t; tw_arr[s0] = w0a[t]; slot0[t] = s0;
    int s1 = atomicAdd(&cursor[e1a[t]], 1);
    tid_arr[s1] = t; tw_arr[s1] = w1a[t]; slot1[t] = s1;
}

// ---------------- fused2: interleaved {1 gemm1 : 2 transpose-w2(64x64)} ----------------
__global__ __launch_bounds__(256, 4) void fused2_kernel(
        const float* __restrict__ w2, bf16* __restrict__ w2t,
        const bf16* __restrict__ xbf, const bf16* __restrict__ w1t,
        const float* __restrict__ b1, const int* __restrict__ offs,
        const int* __restrict__ tid_arr, bf16* __restrict__ hmid,
        const int* __restrict__ tmr, const int* __restrict__ tme, const int* __restrict__ tmn) {
    __shared__ __attribute__((aligned(16))) char smem[16896];
    int bid = blockIdx.x;
    int tid = threadIdx.x;
    int q = bid % 3, h = bid / 3;
    if (q != 0) {
        int tpid = h * 2 + (q - 1);
        if (tpid < 8192) transpose_panel64(w2, w2t, FHD, HD, tpid, tid, smem);
        return;
    }
    // ---- gemm1 section (R14-verbatim structure) ----
    bf16* As = reinterpret_cast<bf16*>(smem);            // 8192 B
    bf16* Bs = reinterpret_cast<bf16*>(smem + 8192);     // 8192 B
    int*  toks = reinterpret_cast<int*>(smem + 16384);   // 512 B
    int orig = h;                          // 0..4351
    int wg = (((3 * orig) & 7) * (NWG1 >> 3)) + (orig >> 3);
    int st = wg / 136, within = wg % 136;
    int tidx = (st >> 2) * 17 + (within % 17);
    int nt = (st & 3) * 8 + (within / 17);
    if (tidx >= tmn[0]) return;
    int e = tme[tidx];
    int row0 = tmr[tidx];
    int s1 = offs[e + 1];
    int n0 = nt * 128;
    if (tid < 128) { int s = row0 + tid; toks[tid] = tid_arr[(s < s1) ? s : (s1 - 1)]; }
    __syncthreads();
    int lane = tid & 63, w = tid >> 6;
    int wrow = (w >> 1) * 64, wcol = (w & 1) * 64;
    int lr = lane & 15, lk = (lane >> 4) * 8;
    int srow = lane >> 2, seg = lane & 3;
    int tokA0 = toks[w * 32 + srow];
    int tokA1 = toks[w * 32 + 16 + srow];
    const bf16* w1e = w1t + (size_t)e * FHD * HD;
    const bf16* bsrc0 = w1e + (size_t)(n0 + w * 32 + srow) * HD + seg * 8;
    const bf16* bsrc1 = w1e + (size_t)(n0 + w * 32 + 16 + srow) * HD + seg * 8;
    const bf16* asrc0 = xbf + (size_t)tokA0 * HD + seg * 8;
    const bf16* asrc1 = xbf + (size_t)tokA1 * HD + seg * 8;
    bf16* aDst0 = &As[(w * 32) * 32];
    bf16* aDst1 = &As[(w * 32 + 16) * 32];
    bf16* bDst0 = &Bs[(w * 32) * 32];
    bf16* bDst1 = &Bs[(w * 32 + 16) * 32];
    f32x4 acc[4][4] = {};
    for (int k0 = 0; k0 < HD; k0 += 32) {
        gload_lds16(asrc0 + k0, aDst0);
        gload_lds16(asrc1 + k0, aDst1);
        gload_lds16(bsrc0 + k0, bDst0);
        gload_lds16(bsrc1 + k0, bDst1);
        __syncthreads();
        s16x8 aF[4], bF[4];
#pragma unroll
        for (int m = 0; m < 4; ++m) aF[m] = *reinterpret_cast<const s16x8*>(&As[(wrow + m * 16 + lr) * 32 + lk]);
#pragma unroll
        for (int n = 0; n < 4; ++n) bF[n] = *reinterpret_cast<const s16x8*>(&Bs[(wcol + n * 16 + lr) * 32 + lk]);
#pragma unroll
        for (int m = 0; m < 4; ++m)
#pragma unroll
            for (int n = 0; n < 4; ++n)
                acc[m][n] = __builtin_amdgcn_mfma_f32_16x16x32_bf16(aF[m], bF[n], acc[m][n], 0, 0, 0);
        __syncthreads();
    }
#pragma unroll
    for (int m = 0; m < 4; ++m) {
#pragma unroll
        for (int n = 0; n < 4; ++n) {
            int col = n0 + wcol + n * 16 + lr;
            float bv = b1[(size_t)e * FHD + col];
#pragma unroll
            for (int r = 0; r < 4; ++r) {
                int row = wrow + m * 16 + (lane >> 4) * 4 + r;
                int slot = row0 + row;
                if (slot < s1) {
                    float v2 = acc[m][n][r] + bv;
                    v2 = 0.5f * v2 * (1.0f + erff(v2 * 0.70710678118f));
                    hmid[(size_t)slot * FHD + col] = __float2bfloat16(v2);
                }
            }
        }
    }
}

// GEMM2 with full-nt 2D supertile decode (17 tidx x 8 nt): hmid fetched once.
__global__ __launch_bounds__(256, 4) void gemm2_kernel(const bf16* __restrict__ hmid, const bf16* __restrict__ w2t,
        const float* __restrict__ b2, const int* __restrict__ offs, bf16* __restrict__ ys,
        const int* __restrict__ tmr, const int* __restrict__ tme, const int* __restrict__ tmn) {
    __shared__ bf16 As[128 * 32];
    __shared__ bf16 Bs[128 * 32];
    int nwg = gridDim.x;              // 1088, %8==0
    int orig = blockIdx.x;
    int wg = (orig & 7) * (nwg >> 3) + (orig >> 3);
    // supertile decode: 136 blocks per supertile = 17 tidx x 8 nt (full n-range)
    int st = wg / 136, within = wg % 136;
    int tidx = st * 17 + (within % 17);
    int nt = within / 17;
    if (tidx >= tmn[0]) return;
    int e = tme[tidx];
    int row0 = tmr[tidx];
    int s1 = offs[e + 1];
    int n0 = nt * 128;
    int tid = threadIdx.x;
    int lane = tid & 63, w = tid >> 6;
    int wrow = (w >> 1) * 64, wcol = (w & 1) * 64;
    int lr = lane & 15, lk = (lane >> 4) * 8;
    int srow = lane >> 2, seg = lane & 3;
    int ar0 = row0 + w * 32 + srow;      if (ar0 >= s1) ar0 = s1 - 1;
    int ar1 = row0 + w * 32 + 16 + srow; if (ar1 >= s1) ar1 = s1 - 1;
    const bf16* w2e = w2t + (size_t)e * HD * FHD;
    const bf16* bsrc0 = w2e + (size_t)(n0 + w * 32 + srow) * FHD + seg * 8;
    const bf16* bsrc1 = w2e + (size_t)(n0 + w * 32 + 16 + srow) * FHD + seg * 8;
    const bf16* asrc0 = hmid + (size_t)ar0 * FHD + seg * 8;
    const bf16* asrc1 = hmid + (size_t)ar1 * FHD + seg * 8;
    bf16* aDst0 = &As[(w * 32) * 32];
    bf16* aDst1 = &As[(w * 32 + 16) * 32];
    bf16* bDst0 = &Bs[(w * 32) * 32];
    bf16* bDst1 = &Bs[(w * 32 + 16) * 32];
    f32x4 acc[4][4] = {};
    for (int k0 = 0; k0 < FHD; k0 += 32) {
        gload_lds16(asrc0 + k0, aDst0);
        gload_lds16(asrc1 + k0, aDst1);
        gload_lds16(bsrc0 + k0, bDst0);
        gload_lds16(bsrc1 + k0, bDst1);
        __syncthreads();
        s16x8 aF[4], bF[4];
#pragma unroll
        for (int m = 0; m < 4; ++m) aF[m] = *reinterpret_cast<const s16x8*>(&As[(wrow + m * 16 + lr) * 32 + lk]);
#pragma unroll
        for (int n = 0; n < 4; ++n) bF[n] = *reinterpret_cast<const s16x8*>(&Bs[(wcol + n * 16 + lr) * 32 + lk]);
#pragma unroll
        for (int m = 0; m < 4; ++m)
#pragma unroll
            for (int n = 0; n < 4; ++n)
                acc[m][n] = __builtin_amdgcn_mfma_f32_16x16x32_bf16(aF[m], bF[n], acc[m][n], 0, 0, 0);
        __syncthreads();
    }
#pragma unroll
    for (int m = 0; m < 4; ++m) {
#pragma unroll
        for (int n = 0; n < 4; ++n) {
            int col = n0 + wcol + n * 16 + lr;
            float bv = b2[(size_t)e * HD + col];
#pragma unroll
            for (int r = 0; r < 4; ++r) {
                int row = wrow + m * 16 + (lane >> 4) * 4 + r;
                int slot = row0 + row;
                if (slot < s1) ys[(size_t)slot * HD + col] = __float2bfloat16(acc[m][n][r] + bv);
            }
        }
    }
}

// out[t,:] = tw[slot0[t]] * ys[slot0[t],:] + tw[slot1[t]] * ys[slot1[t],:]  (ys bf16)
__global__ __launch_bounds__(256) void combine_kernel(const bf16* __restrict__ ys,
        const int* __restrict__ slot0, const int* __restrict__ slot1,
        const float* __restrict__ tw, float* __restrict__ out) {
    int t = blockIdx.x;
    int c = threadIdx.x * 4;
    int sa = slot0[t], sb = slot1[t];
    float wa = tw[sa], wb = tw[sb];
    uint2 araw = *reinterpret_cast<const uint2*>(&ys[(size_t)sa * HD + c]);
    uint2 braw = *reinterpret_cast<const uint2*>(&ys[(size_t)sb * HD + c]);
    const bf16* ab = reinterpret_cast<const bf16*>(&araw);
    const bf16* bb = reinterpret_cast<const bf16*>(&braw);
    float4 o;
    o.x = wa * __bfloat162float(ab[0]) + wb * __bfloat162float(bb[0]);
    o.y = wa * __bfloat162float(ab[1]) + wb * __bfloat162float(bb[1]);
    o.z = wa * __bfloat162float(ab[2]) + wb * __bfloat162float(bb[2]);
    o.w = wa * __bfloat162float(ab[3]) + wb * __bfloat162float(bb[3]);
    *reinterpret_cast<float4*>(&out[(size_t)t * HD + c]) = o;
}

extern "C" void kernel_launch(void* const* d_in, const int* in_sizes, int n_in,
                              void* d_out, int out_size, void* d_ws, size_t ws_size,
                              hipStream_t stream) {
    const float* x  = (const float*)d_in[0];
    const float* rw = (const float*)d_in[1];
    const float* rb = (const float*)d_in[2];
    const float* w1 = (const float*)d_in[3];
    const float* b1 = (const float*)d_in[4];
    const float* w2 = (const float*)d_in[5];
    const float* b2 = (const float*)d_in[6];
    float* out = (float*)d_out;
    char* ws = (char*)d_ws;

    int*   counts  = (int*)(ws + OFF_COUNTS);
    int*   done    = (int*)(ws + OFF_DONE);
    int*   cursor  = (int*)(ws + OFF_CURSOR);
    int*   offs    = (int*)(ws + OFF_OFFS);
    int*   e0a     = (int*)(ws + OFF_E0);
    int*   e1a     = (int*)(ws + OFF_E1);
    float* w0a     = (float*)(ws + OFF_W0);
    float* w1a     = (float*)(ws + OFF_W1);
    int*   slot0   = (int*)(ws + OFF_S0);
    int*   slot1   = (int*)(ws + OFF_S1);
    int*   tid_arr = (int*)(ws + OFF_TID);
    float* tw_arr  = (float*)(ws + OFF_TW);
    int*   tmr     = (int*)(ws + OFF_TMR);
    int*   tme     = (int*)(ws + OFF_TME);
    int*   tmn     = (int*)(ws + OFF_TMN);
    bf16*  xbf     = (bf16*)(ws + OFF_XBF);
    bf16*  w1t     = (bf16*)(ws + OFF_W1T);
    bf16*  w2t     = (bf16*)(ws + OFF_W2T);
    bf16*  hmid    = (bf16*)(ws + OFF_HMID);
    bf16*  ys      = (bf16*)(ws + OFF_YS);

    hipMemsetAsync(counts, 0, 64, stream);   // counts[0..7] + done

    fused1_kernel<<<4096, 256, 0, stream>>>(x, rw, rb, w1, xbf, w1t,
        e0a, e1a, w0a, w1a, counts, done, offs, cursor, tmr, tme, tmn);
    scatter_kernel<<<TT / 256, 256, 0, stream>>>(e0a, e1a, w0a, w1a, cursor,
        tid_arr, tw_arr, slot0, slot1);
    fused2_kernel<<<3 * NWG1, 256, 0, stream>>>(w2, w2t, xbf, w1t, b1, offs,
        tid_arr, hmid, tmr, tme, tmn);
    gemm2_kernel<<<(HD / 128) * NTMAX, 256, 0, stream>>>(hmid, w2t, b2, offs, ys, tmr, tme, tmn);
    combine_kernel<<<TT, 256, 0, stream>>>(ys, slot0, slot1, tw_arr, out);
}